// Round 1
// baseline (688.501 us; speedup 1.0000x reference)
//
#include <hip/hip_runtime.h>
#include <hip/hip_bf16.h>
#include <math.h>

// ---------------- problem constants ----------------
#define B_SZ 2048
#define D_SZ 1024
#define U_SZ 1024
#define L_SZ 3
#define NB 8
#define KAN_K (D_SZ + D_SZ * NB)     // 9216
#define LSTM_K (D_SZ + U_SZ)         // 2048
#define COMB_K (U_SZ + L_SZ * U_SZ)  // 4096
#define LSTM_N (4 * U_SZ)            // 4096

typedef __attribute__((ext_vector_type(8))) short bhalf8_t;  // 8 bf16 in 4 VGPRs
typedef __attribute__((ext_vector_type(4))) float floatx4_t; // MFMA C/D

__device__ inline void async_copy16(const void* g, void* l) {
  __builtin_amdgcn_global_load_lds(
      (const __attribute__((address_space(1))) void*)g,
      (__attribute__((address_space(3))) void*)l, 16, 0, 0);
}

// ---------------- prep: bf16 casts + silu + B-spline bases ----------------
__global__ __launch_bounds__(256) void prep_kernel(
    const float* __restrict__ x, const float* __restrict__ h_prev,
    __hip_bfloat16* __restrict__ A1, __hip_bfloat16* __restrict__ Akan) {
  int idx = blockIdx.x * 256 + threadIdx.x;  // over B*D
  int b = idx >> 10, d = idx & 1023;
  float xv = x[idx];
  float hv = h_prev[idx];
  A1[(size_t)b * LSTM_K + d] = __float2bfloat16(xv);
  A1[(size_t)b * LSTM_K + D_SZ + d] = __float2bfloat16(hv);
  float sg = 1.0f / (1.0f + expf(-xv));
  Akan[(size_t)b * KAN_K + d] = __float2bfloat16(xv * sg);
  // knots: match numpy float32(-1.0 + 0.4*i) computed in double
  float t[12];
#pragma unroll
  for (int i = 0; i < 12; ++i) t[i] = (float)(-1.0 + 0.4 * (double)(i - 3));
  float bb[11];
#pragma unroll
  for (int j = 0; j < 11; ++j) bb[j] = (xv >= t[j] && xv < t[j + 1]) ? 1.0f : 0.0f;
#pragma unroll
  for (int p = 1; p <= 3; ++p) {
#pragma unroll
    for (int j = 0; j + p < 11; ++j) {
      float left = (xv - t[j]) / (t[j + p] - t[j]) * bb[j];
      float right = (t[j + p + 1] - xv) / (t[j + p + 1] - t[j + 1]) * bb[j + 1];
      bb[j] = left + right;
    }
  }
  __hip_bfloat16* dst = Akan + (size_t)b * KAN_K + D_SZ + d * 8;
#pragma unroll
  for (int j = 0; j < 8; ++j) dst[j] = __float2bfloat16(bb[j]);
}

// ---------------- transpose+convert: dst[n*dstLd + k] = bf16(src[k*srcLd + n]) ----------------
__global__ __launch_bounds__(256) void transpose_cvt(
    const float* __restrict__ src, int srcLd,
    __hip_bfloat16* __restrict__ dst, int dstLd, int K, int N) {
  __shared__ float tile[64][65];
  int n0 = blockIdx.x * 64;
  int k0 = blockIdx.y * 64;
  int tx = threadIdx.x & 63;
  int ty = threadIdx.x >> 6;  // 0..3
#pragma unroll
  for (int i = 0; i < 16; ++i) {
    int r = ty + i * 4;
    int k = k0 + r, n = n0 + tx;
    float v = (k < K && n < N) ? src[(size_t)k * srcLd + n] : 0.0f;
    tile[r][tx] = v;
  }
  __syncthreads();
#pragma unroll
  for (int i = 0; i < 16; ++i) {
    int nq = ty + i * 4;
    int n = n0 + nq, k = k0 + tx;
    if (n < N && k < K) dst[(size_t)n * dstLd + k] = __float2bfloat16(tile[tx][nq]);
  }
}

// ---------------- GEMM: C[M,N] = A[M,K](bf16,row) * Bt[N,K](bf16,row) ----------------
// 128x128 block tile, BK=64, 4 waves (2x2), each wave 4x4 of 16x16x32 MFMA.
// XOR swizzle on 16B chunks: LDS is lane-contiguous (global_load_lds constraint),
// swizzle applied to the GLOBAL chunk index at stage time.
// EPI: 0 = f32 store, 1 = bf16 store, 2 = f32 + bias
template <int EPI>
__global__ __launch_bounds__(256) void gemm_bt(
    const __hip_bfloat16* __restrict__ A, const __hip_bfloat16* __restrict__ Bt,
    void* __restrict__ Cout, const float* __restrict__ bias, int K, int ldc) {
  __shared__ __align__(16) char lds[32768];
  char* ldsA = lds;
  char* ldsB = lds + 16384;
  int tid = threadIdx.x;
  int lane = tid & 63;
  int wave = tid >> 6;
  int wm = wave >> 1, wn = wave & 1;
  int q = lane >> 4, l16 = lane & 15;
  int m0 = blockIdx.y * 128, n0 = blockIdx.x * 128;

  floatx4_t acc[4][4];
#pragma unroll
  for (int i = 0; i < 4; ++i)
#pragma unroll
    for (int j = 0; j < 4; ++j) acc[i][j] = (floatx4_t){0.f, 0.f, 0.f, 0.f};

  const __hip_bfloat16* Ab = A + (size_t)m0 * K;
  const __hip_bfloat16* Bb = Bt + (size_t)n0 * K;

  for (int k0 = 0; k0 < K; k0 += 64) {
#pragma unroll
    for (int it = 0; it < 4; ++it) {  // A tile: 128 rows x 64 bf16 = 16KB
      int L = tid + it * 256;         // linear 16B chunk, lane-contiguous
      int n = L >> 3;                 // row in tile
      int c = (L & 7) ^ (n & 7);      // swizzled global chunk
      async_copy16((const char*)(Ab + (size_t)n * K + k0) + c * 16, ldsA + L * 16);
    }
#pragma unroll
    for (int it = 0; it < 4; ++it) {  // B tile
      int L = tid + it * 256;
      int n = L >> 3;
      int c = (L & 7) ^ (n & 7);
      async_copy16((const char*)(Bb + (size_t)n * K + k0) + c * 16, ldsB + L * 16);
    }
    __syncthreads();  // drains vmcnt -> staging complete
#pragma unroll
    for (int s = 0; s < 2; ++s) {  // two K=32 steps
      bhalf8_t af[4], bf[4];
#pragma unroll
      for (int mt = 0; mt < 4; ++mt) {
        int row = wm * 64 + mt * 16 + l16;
        int cl = s * 4 + q;
        int p = cl ^ (row & 7);
        af[mt] = *(const bhalf8_t*)(ldsA + row * 128 + p * 16);
      }
#pragma unroll
      for (int nt = 0; nt < 4; ++nt) {
        int row = wn * 64 + nt * 16 + l16;
        int cl = s * 4 + q;
        int p = cl ^ (row & 7);
        bf[nt] = *(const bhalf8_t*)(ldsB + row * 128 + p * 16);
      }
#pragma unroll
      for (int mt = 0; mt < 4; ++mt)
#pragma unroll
        for (int nt = 0; nt < 4; ++nt)
          acc[mt][nt] = __builtin_amdgcn_mfma_f32_16x16x32_bf16(af[mt], bf[nt], acc[mt][nt], 0, 0, 0);
    }
    __syncthreads();  // protect LDS from next iteration's staging
  }
  // epilogue: C/D layout col=lane&15, row=(lane>>4)*4+reg
#pragma unroll
  for (int mt = 0; mt < 4; ++mt) {
#pragma unroll
    for (int nt = 0; nt < 4; ++nt) {
      int ccol = n0 + wn * 64 + nt * 16 + l16;
#pragma unroll
      for (int i = 0; i < 4; ++i) {
        int crow = m0 + wm * 64 + mt * 16 + q * 4 + i;
        float v = acc[mt][nt][i];
        if (EPI == 0) {
          ((float*)Cout)[(size_t)crow * ldc + ccol] = v;
        } else if (EPI == 1) {
          ((__hip_bfloat16*)Cout)[(size_t)crow * ldc + ccol] = __float2bfloat16(v);
        } else {
          ((float*)Cout)[(size_t)crow * ldc + ccol] = v + bias[ccol];
        }
      }
    }
  }
}

// ---------------- LSTM pointwise gates ----------------
__global__ __launch_bounds__(256) void lstm_pw(
    const float* __restrict__ z, const float* __restrict__ c_prev,
    const float* __restrict__ bias, float* __restrict__ h_out,
    float* __restrict__ c_out, __hip_bfloat16* __restrict__ Acomb) {
  int idx = blockIdx.x * 256 + threadIdx.x;  // over B*U
  int b = idx >> 10, u = idx & 1023;
  const float* zr = z + (size_t)b * LSTM_N;
  float zi = zr[u] + bias[u];
  float zf = zr[U_SZ + u] + bias[U_SZ + u];
  float zg = zr[2 * U_SZ + u] + bias[2 * U_SZ + u];
  float zo = zr[3 * U_SZ + u] + bias[3 * U_SZ + u];
  float si = 1.f / (1.f + expf(-zi));
  float sf = 1.f / (1.f + expf(-zf));
  float so = 1.f / (1.f + expf(-zo));
  float c = sf * c_prev[idx] + si * tanhf(zg);
  float h = so * tanhf(c);
  h_out[idx] = h;
  c_out[idx] = c;
  Acomb[(size_t)b * COMB_K + u] = __float2bfloat16(h);
}

// ---------------- launcher ----------------
extern "C" void kernel_launch(void* const* d_in, const int* in_sizes, int n_in,
                              void* d_out, int out_size, void* d_ws, size_t ws_size,
                              hipStream_t stream) {
  const float* x        = (const float*)d_in[0];
  const float* h_prev   = (const float*)d_in[1];
  const float* c_prev   = (const float*)d_in[2];
  const float* lstm_k   = (const float*)d_in[3];
  const float* lstm_r   = (const float*)d_in[4];
  const float* lstm_b   = (const float*)d_in[5];
  const float* base_w   = (const float*)d_in[6];
  const float* spline_w = (const float*)d_in[7];
  const float* comb_w   = (const float*)d_in[8];
  const float* comb_b   = (const float*)d_in[9];
  float* out = (float*)d_out;  // [output | h | c], each B*U f32

  char* ws = (char*)d_ws;
  auto alloc = [&](size_t bytes) {
    char* p = ws;
    ws += (bytes + 255) & ~(size_t)255;
    return p;
  };
  __hip_bfloat16* A1    = (__hip_bfloat16*)alloc((size_t)B_SZ * LSTM_K * 2);   // [x|h_prev]
  __hip_bfloat16* Akan  = (__hip_bfloat16*)alloc((size_t)B_SZ * KAN_K * 2);    // [silu|bases]
  __hip_bfloat16* Acomb = (__hip_bfloat16*)alloc((size_t)B_SZ * COMB_K * 2);   // [h|kan]
  __hip_bfloat16* Bt1   = (__hip_bfloat16*)alloc((size_t)LSTM_N * LSTM_K * 2); // [4096,2048]
  __hip_bfloat16* Btk   = (__hip_bfloat16*)alloc((size_t)(L_SZ * U_SZ) * KAN_K * 2); // [3072,9216]
  __hip_bfloat16* Btc   = (__hip_bfloat16*)alloc((size_t)U_SZ * COMB_K * 2);   // [1024,4096]
  float* z              = (float*)alloc((size_t)B_SZ * LSTM_N * 4);            // [2048,4096]

  // 1) activations + bases
  prep_kernel<<<dim3(B_SZ * D_SZ / 256), dim3(256), 0, stream>>>(x, h_prev, A1, Akan);

  // 2) weight transposes (f32 [K,N] -> bf16 [N,K])
  transpose_cvt<<<dim3(LSTM_N / 64, D_SZ / 64), 256, 0, stream>>>(lstm_k, LSTM_N, Bt1, LSTM_K, D_SZ, LSTM_N);
  transpose_cvt<<<dim3(LSTM_N / 64, U_SZ / 64), 256, 0, stream>>>(lstm_r, LSTM_N, Bt1 + D_SZ, LSTM_K, U_SZ, LSTM_N);
  transpose_cvt<<<dim3(U_SZ / 64, COMB_K / 64), 256, 0, stream>>>(comb_w, U_SZ, Btc, COMB_K, COMB_K, U_SZ);
  for (int l = 0; l < L_SZ; ++l) {
    transpose_cvt<<<dim3(U_SZ / 64, D_SZ / 64), 256, 0, stream>>>(
        base_w + (size_t)l * D_SZ * U_SZ, U_SZ,
        Btk + (size_t)l * U_SZ * KAN_K, KAN_K, D_SZ, U_SZ);
    transpose_cvt<<<dim3(U_SZ / 64, (D_SZ * NB) / 64), 256, 0, stream>>>(
        spline_w + (size_t)l * D_SZ * NB * U_SZ, U_SZ,
        Btk + (size_t)l * U_SZ * KAN_K + D_SZ, KAN_K, D_SZ * NB, U_SZ);
  }

  // 3) z = [x|h] @ [Wl;Rl]   (M=2048,N=4096,K=2048)
  gemm_bt<0><<<dim3(LSTM_N / 128, B_SZ / 128), 256, 0, stream>>>(A1, Bt1, z, nullptr, LSTM_K, LSTM_N);
  // 4) kan = [silu|bases] @ [base;spline] for all 3 layers (N=3072,K=9216) -> bf16 into Acomb cols 1024..
  gemm_bt<1><<<dim3((L_SZ * U_SZ) / 128, B_SZ / 128), 256, 0, stream>>>(Akan, Btk, (void*)(Acomb + U_SZ), nullptr, KAN_K, COMB_K);
  // 5) gates -> h,c outputs + h bf16 into Acomb cols 0..1023
  lstm_pw<<<dim3(B_SZ * U_SZ / 256), 256, 0, stream>>>(z, c_prev, lstm_b,
                                                       out + (size_t)B_SZ * U_SZ,
                                                       out + 2 * (size_t)B_SZ * U_SZ, Acomb);
  // 6) output = [h|kan] @ combine_w + b  (N=1024,K=4096)
  gemm_bt<2><<<dim3(U_SZ / 128, B_SZ / 128), 256, 0, stream>>>(Acomb, Btc, out, comb_b, COMB_K, U_SZ);
}

// Round 2
// 577.375 us; speedup vs baseline: 1.1925x; 1.1925x over previous
//
#include <hip/hip_runtime.h>
#include <hip/hip_bf16.h>
#include <math.h>

// ---------------- problem constants ----------------
#define B_SZ 2048
#define D_SZ 1024
#define U_SZ 1024
#define L_SZ 3
#define NB 8
#define KAN_K (D_SZ + D_SZ * NB)     // 9216
#define KAN_N (L_SZ * U_SZ)          // 3072
#define LSTM_K (D_SZ + U_SZ)         // 2048
#define COMB_K (U_SZ + L_SZ * U_SZ)  // 4096
#define LSTM_N (4 * U_SZ)            // 4096

typedef __attribute__((ext_vector_type(8))) short bhalf8_t;  // 8 bf16 in 4 VGPRs
typedef __attribute__((ext_vector_type(4))) float floatx4_t; // MFMA C/D

__device__ inline void async_copy16(const void* g, void* l) {
  __builtin_amdgcn_global_load_lds(
      (const __attribute__((address_space(1))) void*)g,
      (__attribute__((address_space(3))) void*)l, 16, 0, 0);
}

// =================================================================
// Kernel 1: prep (bf16 casts + silu + bases) fused with ALL weight
// transposes (f32 [K,N] -> bf16 [N,K]) via linear-block-id decode.
// Blocks: [0,8192) prep over B*D; [8192,18176) transpose jobs.
// =================================================================
__global__ __launch_bounds__(256) void prep_trans(
    const float* __restrict__ x, const float* __restrict__ h_prev,
    const float* __restrict__ lstm_k, const float* __restrict__ lstm_r,
    const float* __restrict__ comb_w, const float* __restrict__ base_w,
    const float* __restrict__ spline_w,
    __hip_bfloat16* __restrict__ A1, __hip_bfloat16* __restrict__ Akan,
    __hip_bfloat16* __restrict__ Bt1, __hip_bfloat16* __restrict__ Btc,
    __hip_bfloat16* __restrict__ Btk) {
  __shared__ float tile[64][65];
  int bid = blockIdx.x;
  int tid = threadIdx.x;
  if (bid < 8192) {
    // ---- prep path ----
    int idx = bid * 256 + tid;  // over B*D
    int b = idx >> 10, d = idx & 1023;
    float xv = x[idx];
    float hv = h_prev[idx];
    A1[(size_t)b * LSTM_K + d] = __float2bfloat16(xv);
    A1[(size_t)b * LSTM_K + D_SZ + d] = __float2bfloat16(hv);
    float sg = 1.0f / (1.0f + expf(-xv));
    Akan[(size_t)b * KAN_K + d] = __float2bfloat16(xv * sg);
    float t[12];
#pragma unroll
    for (int i = 0; i < 12; ++i) t[i] = (float)(-1.0 + 0.4 * (double)(i - 3));
    float bb[11];
#pragma unroll
    for (int j = 0; j < 11; ++j) bb[j] = (xv >= t[j] && xv < t[j + 1]) ? 1.0f : 0.0f;
#pragma unroll
    for (int p = 1; p <= 3; ++p) {
#pragma unroll
      for (int j = 0; j + p < 11; ++j) {
        float left = (xv - t[j]) / (t[j + p] - t[j]) * bb[j];
        float right = (t[j + p + 1] - xv) / (t[j + p + 1] - t[j + 1]) * bb[j + 1];
        bb[j] = left + right;
      }
    }
    __hip_bfloat16* dst = Akan + (size_t)b * KAN_K + D_SZ + d * 8;
#pragma unroll
    for (int j = 0; j < 8; ++j) dst[j] = __float2bfloat16(bb[j]);
    return;
  }
  // ---- transpose path: decode job ----
  int id = bid - 8192;
  const float* src;
  __hip_bfloat16* dst;
  int srcLd, dstLd, gxs;  // gxs = log2(gridX)
  if (id < 1024) {            // lstm_kernel [1024,4096] -> Bt1[:,0:1024]
    src = lstm_k; dst = Bt1; srcLd = 4096; dstLd = 2048; gxs = 6;
  } else if (id < 2048) {     // lstm_rkernel [1024,4096] -> Bt1[:,1024:2048]
    id -= 1024; src = lstm_r; dst = Bt1 + 1024; srcLd = 4096; dstLd = 2048; gxs = 6;
  } else if (id < 3072) {     // combine_w [4096,1024] -> Btc
    id -= 2048; src = comb_w; dst = Btc; srcLd = 1024; dstLd = 4096; gxs = 4;
  } else if (id < 3840) {     // base_w l: [1024,1024] -> Btk[l][:,0:1024]
    id -= 3072; int l = id >> 8; id &= 255;
    src = base_w + (size_t)l * 1048576;
    dst = Btk + (size_t)l * U_SZ * KAN_K;
    srcLd = 1024; dstLd = KAN_K; gxs = 4;
  } else {                    // spline_w l: [8192,1024] -> Btk[l][:,1024:9216]
    id -= 3840; int l = id >> 11; id &= 2047;
    src = spline_w + (size_t)l * 8388608;
    dst = Btk + (size_t)l * U_SZ * KAN_K + D_SZ;
    srcLd = 1024; dstLd = KAN_K; gxs = 4;
  }
  int n0 = (id & ((1 << gxs) - 1)) * 64;
  int k0 = (id >> gxs) * 64;
  int tx = tid & 63;
  int ty = tid >> 6;  // 0..3
#pragma unroll
  for (int i = 0; i < 16; ++i) {
    int r = ty + i * 4;
    tile[r][tx] = src[(size_t)(k0 + r) * srcLd + n0 + tx];
  }
  __syncthreads();
#pragma unroll
  for (int i = 0; i < 16; ++i) {
    int nq = ty + i * 4;
    dst[(size_t)(n0 + nq) * dstLd + k0 + tx] = __float2bfloat16(tile[tx][nq]);
  }
}

// =================================================================
// GEMM core: C[m0:+128, n0:+128] (+)= A[m0:+128, kBeg:kEnd] * Bt[n0:+128, kBeg:kEnd]^T
// A,Bt bf16 row-major with row stride lda. C f32 row stride ldc (overwrite).
// 128x128 tile, BK=64, 4 waves (2x2), 4x4 of 16x16x32 MFMA per wave.
// XOR-swizzled 16B chunks (zero bank conflicts, verified round 1).
// =================================================================
__device__ __forceinline__ void gemm_core(
    const __hip_bfloat16* __restrict__ A, const __hip_bfloat16* __restrict__ Bt,
    int lda, float* __restrict__ C, int ldc, int m0, int n0, int kBeg, int kEnd) {
  __shared__ __align__(16) char lds[32768];
  char* ldsA = lds;
  char* ldsB = lds + 16384;
  int tid = threadIdx.x;
  int lane = tid & 63;
  int wave = tid >> 6;
  int wm = wave >> 1, wn = wave & 1;
  int q = lane >> 4, l16 = lane & 15;

  floatx4_t acc[4][4];
#pragma unroll
  for (int i = 0; i < 4; ++i)
#pragma unroll
    for (int j = 0; j < 4; ++j) acc[i][j] = (floatx4_t){0.f, 0.f, 0.f, 0.f};

  const __hip_bfloat16* Ab = A + (size_t)m0 * lda;
  const __hip_bfloat16* Bb = Bt + (size_t)n0 * lda;

  for (int k0 = kBeg; k0 < kEnd; k0 += 64) {
#pragma unroll
    for (int it = 0; it < 4; ++it) {  // A tile: 128 rows x 64 bf16 = 16KB
      int L = tid + it * 256;         // linear 16B chunk, lane-contiguous
      int n = L >> 3;
      int c = (L & 7) ^ (n & 7);
      async_copy16((const char*)(Ab + (size_t)n * lda + k0) + c * 16, ldsA + L * 16);
    }
#pragma unroll
    for (int it = 0; it < 4; ++it) {  // B tile
      int L = tid + it * 256;
      int n = L >> 3;
      int c = (L & 7) ^ (n & 7);
      async_copy16((const char*)(Bb + (size_t)n * lda + k0) + c * 16, ldsB + L * 16);
    }
    __syncthreads();
#pragma unroll
    for (int s = 0; s < 2; ++s) {
      bhalf8_t af[4], bf[4];
#pragma unroll
      for (int mt = 0; mt < 4; ++mt) {
        int row = wm * 64 + mt * 16 + l16;
        int p = (s * 4 + q) ^ (row & 7);
        af[mt] = *(const bhalf8_t*)(ldsA + row * 128 + p * 16);
      }
#pragma unroll
      for (int nt = 0; nt < 4; ++nt) {
        int row = wn * 64 + nt * 16 + l16;
        int p = (s * 4 + q) ^ (row & 7);
        bf[nt] = *(const bhalf8_t*)(ldsB + row * 128 + p * 16);
      }
#pragma unroll
      for (int mt = 0; mt < 4; ++mt)
#pragma unroll
        for (int nt = 0; nt < 4; ++nt)
          acc[mt][nt] = __builtin_amdgcn_mfma_f32_16x16x32_bf16(af[mt], bf[nt], acc[mt][nt], 0, 0, 0);
    }
    __syncthreads();
  }
  // epilogue: C/D layout col=lane&15, row=(lane>>4)*4+reg
#pragma unroll
  for (int mt = 0; mt < 4; ++mt) {
#pragma unroll
    for (int nt = 0; nt < 4; ++nt) {
      int ccol = n0 + wn * 64 + nt * 16 + l16;
#pragma unroll
      for (int i = 0; i < 4; ++i) {
        int crow = m0 + wm * 64 + mt * 16 + q * 4 + i;
        C[(size_t)crow * ldc + ccol] = acc[mt][nt][i];
      }
    }
  }
}

// =================================================================
// Kernel 2: merged LSTM GEMM + KAN GEMM (split-K=2) in one dispatch.
// Blocks [0,512): z = A1 @ Bt1^T (M=2048,N=4096,K=2048)
// Blocks [512,1280): Pkan[sk] = Akan @ Btk^T over K-chunk sk (4608 each)
// =================================================================
__global__ __launch_bounds__(256) void gemm_multi(
    const __hip_bfloat16* __restrict__ A1, const __hip_bfloat16* __restrict__ Bt1,
    const __hip_bfloat16* __restrict__ Akan, const __hip_bfloat16* __restrict__ Btk,
    float* __restrict__ z, float* __restrict__ Pkan) {
  int id = blockIdx.x;
  if (id < 512) {
    int n0 = (id & 31) * 128;
    int m0 = (id >> 5) * 128;
    gemm_core(A1, Bt1, LSTM_K, z, LSTM_N, m0, n0, 0, LSTM_K);
  } else {
    int id2 = id - 512;
    int sk = id2 >= 384;
    int rem = id2 - sk * 384;
    int n0 = (rem % 24) * 128;
    int m0 = (rem / 24) * 128;
    gemm_core(Akan, Btk, KAN_K, Pkan + (size_t)sk * B_SZ * KAN_N, KAN_N,
              m0, n0, sk * 4608, (sk + 1) * 4608);
  }
}

// =================================================================
// Kernel 3: fused LSTM pointwise gates + KAN split-K reduce (->bf16 Acomb)
// Blocks [0,8192): gates over B*U; [8192,14336): reduce over B*KAN_N (x4 vec)
// =================================================================
__global__ __launch_bounds__(256) void reduce_fuse(
    const float* __restrict__ z, const float* __restrict__ c_prev,
    const float* __restrict__ bias, const float* __restrict__ Pkan,
    float* __restrict__ h_out, float* __restrict__ c_out,
    __hip_bfloat16* __restrict__ Acomb) {
  int bid = blockIdx.x;
  int tid = threadIdx.x;
  if (bid < 8192) {
    int idx = bid * 256 + tid;  // over B*U
    int b = idx >> 10, u = idx & 1023;
    const float* zr = z + (size_t)b * LSTM_N;
    float zi = zr[u] + bias[u];
    float zf = zr[U_SZ + u] + bias[U_SZ + u];
    float zg = zr[2 * U_SZ + u] + bias[2 * U_SZ + u];
    float zo = zr[3 * U_SZ + u] + bias[3 * U_SZ + u];
    float si = 1.f / (1.f + expf(-zi));
    float sf = 1.f / (1.f + expf(-zf));
    float so = 1.f / (1.f + expf(-zo));
    float c = sf * c_prev[idx] + si * tanhf(zg);
    float h = so * tanhf(c);
    h_out[idx] = h;
    c_out[idx] = c;
    Acomb[(size_t)b * COMB_K + u] = __float2bfloat16(h);
  } else {
    int g = (bid - 8192) * 256 + tid;  // over B*KAN_N/4
    int m = g / (KAN_N / 4);
    int c4 = (g - m * (KAN_N / 4)) * 4;
    const float4 p0 = *(const float4*)(Pkan + (size_t)m * KAN_N + c4);
    const float4 p1 = *(const float4*)(Pkan + (size_t)B_SZ * KAN_N + (size_t)m * KAN_N + c4);
    __hip_bfloat16 o[4];
    o[0] = __float2bfloat16(p0.x + p1.x);
    o[1] = __float2bfloat16(p0.y + p1.y);
    o[2] = __float2bfloat16(p0.z + p1.z);
    o[3] = __float2bfloat16(p0.w + p1.w);
    *(ushort4*)(Acomb + (size_t)m * COMB_K + U_SZ + c4) = *(ushort4*)o;
  }
}

// =================================================================
// Kernel 4: combine GEMM split-K=4 -> Pcomb partials
// 512 blocks: sk=id>>7; rem: bx=rem&7 (N=1024), by=rem>>3 (M=2048)
// =================================================================
__global__ __launch_bounds__(256) void gemm_comb(
    const __hip_bfloat16* __restrict__ Acomb, const __hip_bfloat16* __restrict__ Btc,
    float* __restrict__ Pcomb) {
  int id = blockIdx.x;
  int sk = id >> 7;
  int rem = id & 127;
  int n0 = (rem & 7) * 128;
  int m0 = (rem >> 3) * 128;
  gemm_core(Acomb, Btc, COMB_K, Pcomb + (size_t)sk * B_SZ * U_SZ, U_SZ,
            m0, n0, sk * 1024, (sk + 1) * 1024);
}

// Kernel 5: reduce 4 combine partials + bias -> out (f32)
__global__ __launch_bounds__(256) void comb_reduce(
    const float* __restrict__ Pcomb, const float* __restrict__ bias,
    float* __restrict__ out) {
  int g = blockIdx.x * 256 + threadIdx.x;  // over B*U/4
  int m = g >> 8;
  int c4 = (g & 255) * 4;
  float4 s = *(const float4*)(Pcomb + (size_t)m * U_SZ + c4);
  const size_t stride = (size_t)B_SZ * U_SZ;
#pragma unroll
  for (int p = 1; p < 4; ++p) {
    float4 t = *(const float4*)(Pcomb + stride * p + (size_t)m * U_SZ + c4);
    s.x += t.x; s.y += t.y; s.z += t.z; s.w += t.w;
  }
  float4 bv = *(const float4*)(bias + c4);
  s.x += bv.x; s.y += bv.y; s.z += bv.z; s.w += bv.w;
  *(float4*)(out + (size_t)m * U_SZ + c4) = s;
}

// ---------------- launcher ----------------
extern "C" void kernel_launch(void* const* d_in, const int* in_sizes, int n_in,
                              void* d_out, int out_size, void* d_ws, size_t ws_size,
                              hipStream_t stream) {
  const float* x        = (const float*)d_in[0];
  const float* h_prev   = (const float*)d_in[1];
  const float* c_prev   = (const float*)d_in[2];
  const float* lstm_k   = (const float*)d_in[3];
  const float* lstm_r   = (const float*)d_in[4];
  const float* lstm_b   = (const float*)d_in[5];
  const float* base_w   = (const float*)d_in[6];
  const float* spline_w = (const float*)d_in[7];
  const float* comb_w   = (const float*)d_in[8];
  const float* comb_b   = (const float*)d_in[9];
  float* out = (float*)d_out;  // [output | h | c], each B*U f32

  char* ws = (char*)d_ws;
  auto alloc = [&](size_t bytes) {
    char* p = ws;
    ws += (bytes + 255) & ~(size_t)255;
    return p;
  };
  __hip_bfloat16* A1    = (__hip_bfloat16*)alloc((size_t)B_SZ * LSTM_K * 2);
  __hip_bfloat16* Akan  = (__hip_bfloat16*)alloc((size_t)B_SZ * KAN_K * 2);
  __hip_bfloat16* Acomb = (__hip_bfloat16*)alloc((size_t)B_SZ * COMB_K * 2);
  __hip_bfloat16* Bt1   = (__hip_bfloat16*)alloc((size_t)LSTM_N * LSTM_K * 2);
  __hip_bfloat16* Btk   = (__hip_bfloat16*)alloc((size_t)KAN_N * KAN_K * 2);
  __hip_bfloat16* Btc   = (__hip_bfloat16*)alloc((size_t)U_SZ * COMB_K * 2);
  float* z              = (float*)alloc((size_t)B_SZ * LSTM_N * 4);
  float* Pkan           = (float*)alloc((size_t)2 * B_SZ * KAN_N * 4);
  float* Pcomb          = Pkan;  // alias: Pkan dead after reduce_fuse; 50.3MB >= 33.5MB

  // 1) prep + all weight transposes (one dispatch, 18176 blocks)
  prep_trans<<<dim3(18176), 256, 0, stream>>>(x, h_prev, lstm_k, lstm_r, comb_w,
                                              base_w, spline_w, A1, Akan, Bt1, Btc, Btk);
  // 2) LSTM GEMM + KAN GEMM split-K=2 (one dispatch, 1280 blocks)
  gemm_multi<<<dim3(1280), 256, 0, stream>>>(A1, Bt1, Akan, Btk, z, Pkan);
  // 3) gates + KAN reduce -> Acomb
  reduce_fuse<<<dim3(14336), 256, 0, stream>>>(z, c_prev, lstm_b, Pkan,
                                               out + (size_t)B_SZ * U_SZ,
                                               out + 2 * (size_t)B_SZ * U_SZ, Acomb);
  // 4) combine GEMM split-K=4 -> partials
  gemm_comb<<<dim3(512), 256, 0, stream>>>(Acomb, Btc, Pcomb);
  // 5) reduce + bias -> out
  comb_reduce<<<dim3(2048), 256, 0, stream>>>(Pcomb, comb_b, out);
}